// Round 6
// baseline (337.106 us; speedup 1.0000x reference)
//
#include <hip/hip_runtime.h>
#include <hip/hip_bf16.h>

// ParallelExperts: per-expert LayerNorm -> Linear(1024->4096) -> tanh-GELU
// E=16 experts, 512 tokens each (balanced), fp32 in/out, bf16 MFMA inside.

#define E_EXP 16
#define T_TOK 8192
#define DIN   1024
#define DOUT  4096

typedef __bf16 bf16;
typedef __bf16 bf16x4v __attribute__((ext_vector_type(4)));
typedef __bf16 bf16x8v __attribute__((ext_vector_type(8)));
typedef float  f32x4   __attribute__((ext_vector_type(4)));

typedef __attribute__((address_space(1))) void gvoid;
typedef __attribute__((address_space(3))) void lvoid;

// ---------------- LayerNorm -> bf16 (one block per token) ----------------
__global__ __launch_bounds__(256) void ln_bf16_kernel(
    const float* __restrict__ x, const float* __restrict__ gamma,
    const float* __restrict__ beta, bf16* __restrict__ xn) {
  const int t    = blockIdx.x;
  const int e    = t >> 9;            // 512 tokens per expert
  const int tid  = threadIdx.x;
  const float4 xv = reinterpret_cast<const float4*>(x + (size_t)t * DIN)[tid];
  float s  = xv.x + xv.y + xv.z + xv.w;
  float s2 = xv.x * xv.x + xv.y * xv.y + xv.z * xv.z + xv.w * xv.w;
#pragma unroll
  for (int o = 32; o > 0; o >>= 1) {
    s  += __shfl_xor(s,  o, 64);
    s2 += __shfl_xor(s2, o, 64);
  }
  __shared__ float red[8];
  const int lane = tid & 63, wid = tid >> 6;
  if (lane == 0) { red[wid] = s; red[4 + wid] = s2; }
  __syncthreads();
  s  = red[0] + red[1] + red[2] + red[3];
  s2 = red[4] + red[5] + red[6] + red[7];
  const float mu  = s * (1.0f / DIN);
  const float var = s2 * (1.0f / DIN) - mu * mu;
  const float inv = rsqrtf(var + 1e-5f);
  const float4 g = reinterpret_cast<const float4*>(gamma + (size_t)e * DIN)[tid];
  const float4 b = reinterpret_cast<const float4*>(beta  + (size_t)e * DIN)[tid];
  bf16x4v o;
  o[0] = (bf16)((xv.x - mu) * inv * g.x + b.x);
  o[1] = (bf16)((xv.y - mu) * inv * g.y + b.y);
  o[2] = (bf16)((xv.z - mu) * inv * g.z + b.z);
  o[3] = (bf16)((xv.w - mu) * inv * g.w + b.w);
  *reinterpret_cast<bf16x4v*>(xn + (size_t)t * DIN + tid * 4) = o;
}

// ---------------- grouped GEMM: C = GELU(xn @ W[e] + b[e]) ----------------
// 256x256 tile, K-tile 64, 8 waves (2m x 4n), per-wave 128x64 output.
// 4 phases per K-tile, 16 MFMA each:
//   phase: [ds_reads | staging chunk] -> barrier -> lgkmcnt(0) ->
//          setprio(1) 16xMFMA setprio(0) -> barrier
// A: global_load_lds (linear dest) with pre-swizzled SOURCE (grp ^= row&7),
//    reads swizzled to match -> <=2-way banks.
// B: fp32 float2 column loads (coalesced), 2-tile register prefetch, cvt to
//    bf16, ds_write with grp ^= (n>>1)&7 swizzle (writes+reads conflict-free).
// vmcnt counted once per K-tile: next B tile (16 loads) stays in flight.
#define BM 256
#define BN 256
#define BKT 64
#define NKT (DIN / BKT)   // 16 K-tiles

#define SCHED_FENCE __builtin_amdgcn_sched_barrier(0)

__global__ __launch_bounds__(512, 2) void grouped_gemm_kernel(
    const bf16* __restrict__ xn, const float* __restrict__ W,
    const float* __restrict__ bias, float* __restrict__ out) {
  __shared__ bf16 Alds[2][BM * BKT];   // 2 x 32 KB, [m][64] grp^(m&7)
  __shared__ bf16 Blds[2][BN * BKT];   // 2 x 32 KB, [n][64] grp^((n>>1)&7)

  const int tid    = threadIdx.x;
  const int lane   = tid & 63;
  const int wid    = tid >> 6;       // 0..7
  const int warp_m = wid >> 2;       // 0..1
  const int warp_n = wid & 3;        // 0..3

  // bijective XCD swizzle: 512 blocks, 8 XCDs, 64 contiguous per XCD.
  const int swz    = (blockIdx.x & 7) * 64 + (blockIdx.x >> 3);
  const int ntile  = swz & 15;       // 0..15
  const int mtile  = swz >> 4;       // 0..31
  const int e      = mtile >> 1;     // 2 m-tiles per expert
  const int t0     = mtile * BM;
  const int n0     = ntile * BN;

  f32x4 acc[8][4];
#pragma unroll
  for (int i = 0; i < 8; ++i)
#pragma unroll
    for (int j = 0; j < 4; ++j)
      acc[i][j] = (f32x4){0.f, 0.f, 0.f, 0.f};

  const bf16*  Abase = xn + (size_t)t0 * DIN;
  const float* Wbase = W + (size_t)e * DIN * DOUT + n0;

  // fragment-read swizzle constants (lane-only)
  const int g0a  = (lane >> 4) ^ (lane & 7);          // A phys grp, ks=0
  const int h0b  = (lane >> 4) ^ ((lane >> 1) & 7);   // B phys grp, ks=0
  const int arow = warp_m * 128 + (lane & 15);
  const int brow = warp_n * 64 + (lane & 15);
  // A staging: logical source group so linear LDS dest ends up swizzled
  const int alg  = (lane & 7) ^ ((lane >> 3) & 7);

  // B staging ownership: col pair 2*np..2*np+1, k-quarter kq (16 k's)
  const int np = tid & 127;
  const int kq = tid >> 7;

  float2 sA[16], sB[16];   // two B register sets (2-tile prefetch)

#define STAGE_A2(buf, k0, J0)                                                 \
  {                                                                           \
    _Pragma("unroll")                                                         \
    for (int j = (J0); j < (J0) + 2; ++j) {                                   \
      const int c2 = wid * 4 + j;                  /* 0..31: rows c2*8..+7 */ \
      const bf16* g = Abase + (size_t)(c2 * 8 + (lane >> 3)) * DIN + (k0) +   \
                      alg * 8;                                                \
      __builtin_amdgcn_global_load_lds((gvoid*)g,                             \
                                       (lvoid*)&Alds[buf][c2 * 512], 16, 0, 0); \
    }                                                                         \
  }

#define LOAD_B4(S, k0, Q)                                                     \
  {                                                                           \
    _Pragma("unroll")                                                         \
    for (int r = 0; r < 4; ++r) {                                             \
      const int rr = (Q) * 4 + r;                                             \
      S[rr] = *reinterpret_cast<const float2*>(                               \
          Wbase + (size_t)((k0) + kq * 16 + rr) * DOUT + 2 * np);             \
    }                                                                         \
  }

#define WRITE_B(S, buf)                                                       \
  {                                                                           \
    bf16x8v v0, v1, v2, v3;                                                   \
    _Pragma("unroll")                                                         \
    for (int r = 0; r < 8; ++r) {                                             \
      v0[r] = (bf16)S[r].x;  v1[r] = (bf16)S[r + 8].x;                        \
      v2[r] = (bf16)S[r].y;  v3[r] = (bf16)S[r + 8].y;                        \
    }                                                                         \
    const int c0 = 2 * np, slot = np & 7;                                     \
    *(bf16x8v*)&Blds[buf][c0 * BKT + (((2 * kq) ^ slot) * 8)]           = v0; \
    *(bf16x8v*)&Blds[buf][c0 * BKT + (((2 * kq + 1) ^ slot) * 8)]       = v1; \
    *(bf16x8v*)&Blds[buf][(c0 + 1) * BKT + (((2 * kq) ^ slot) * 8)]     = v2; \
    *(bf16x8v*)&Blds[buf][(c0 + 1) * BKT + (((2 * kq + 1) ^ slot) * 8)] = v3; \
  }

#define RD_A4(MIB, KS)                                                        \
  {                                                                           \
    _Pragma("unroll")                                                         \
    for (int mi = 0; mi < 4; ++mi)                                            \
      af[mi] = *reinterpret_cast<const bf16x8v*>(                             \
          &Alds[cur][(arow + ((MIB) + mi) * 16) * BKT +                       \
                     ((g0a ^ ((KS) * 4)) * 8)]);                              \
  }

#define RD_B4(KS)                                                             \
  {                                                                           \
    _Pragma("unroll")                                                         \
    for (int ni = 0; ni < 4; ++ni)                                            \
      bfr[ni] = *reinterpret_cast<const bf16x8v*>(                            \
          &Blds[cur][(brow + ni * 16) * BKT + ((h0b ^ ((KS) * 4)) * 8)]);     \
  }

#define MFMA_Q(MIB)                                                           \
  {                                                                           \
    _Pragma("unroll")                                                         \
    for (int mi = 0; mi < 4; ++mi)                                            \
      _Pragma("unroll")                                                       \
      for (int ni = 0; ni < 4; ++ni)                                          \
        acc[(MIB) + mi][ni] = __builtin_amdgcn_mfma_f32_16x16x32_bf16(        \
            af[mi], bfr[ni], acc[(MIB) + mi][ni], 0, 0, 0);                   \
  }

#define PHASE_SYNC_IN                                                         \
  SCHED_FENCE;                                                                \
  __builtin_amdgcn_s_barrier();                                               \
  asm volatile("s_waitcnt lgkmcnt(0)" ::: "memory");                          \
  SCHED_FENCE;

#define PHASE_SYNC_OUT                                                        \
  SCHED_FENCE;                                                                \
  __builtin_amdgcn_s_barrier();

// One K-tile = 4 phases x 16 MFMA. SL receives B(KT+2); SW (holding B(KT+1))
// is cvt'd + written to LDS buf cur^1 in phase 3.
#define K_TILE(KT, SL, SW)                                                    \
  {                                                                           \
    const int cur = (KT) & 1;                                                 \
    bf16x8v af[4], bfr[4];                                                    \
    /* phase 0: ks=0, mi 0-3 */                                               \
    RD_A4(0, 0); RD_B4(0);                                                    \
    if ((KT) + 1 < NKT) STAGE_A2(cur ^ 1, ((KT) + 1) * BKT, 0);               \
    if ((KT) + 2 < NKT) LOAD_B4(SL, ((KT) + 2) * BKT, 0);                     \
    PHASE_SYNC_IN;                                                            \
    __builtin_amdgcn_s_setprio(1); MFMA_Q(0); __builtin_amdgcn_s_setprio(0);  \
    PHASE_SYNC_OUT;                                                           \
    /* phase 1: ks=0, mi 4-7 (bfr reused) */                                  \
    RD_A4(4, 0);                                                              \
    if ((KT) + 1 < NKT) STAGE_A2(cur ^ 1, ((KT) + 1) * BKT, 2);               \
    if ((KT) + 2 < NKT) LOAD_B4(SL, ((KT) + 2) * BKT, 1);                     \
    PHASE_SYNC_IN;                                                            \
    __builtin_amdgcn_s_setprio(1); MFMA_Q(4); __builtin_amdgcn_s_setprio(0);  \
    PHASE_SYNC_OUT;                                                           \
    /* phase 2: ks=1, mi 0-3 */                                               \
    RD_A4(0, 1); RD_B4(1);                                                    \
    if ((KT) + 2 < NKT) LOAD_B4(SL, ((KT) + 2) * BKT, 2);                     \
    PHASE_SYNC_IN;                                                            \
    __builtin_amdgcn_s_setprio(1); MFMA_Q(0); __builtin_amdgcn_s_setprio(0);  \
    PHASE_SYNC_OUT;                                                           \
    /* phase 3: ks=1, mi 4-7; write B(KT+1); counted vmcnt */                 \
    RD_A4(4, 1);                                                              \
    if ((KT) + 2 < NKT) LOAD_B4(SL, ((KT) + 2) * BKT, 3);                     \
    if ((KT) + 1 < NKT) WRITE_B(SW, cur ^ 1);                                 \
    SCHED_FENCE;                                                              \
    if ((KT) + 2 < NKT) {                                                     \
      asm volatile("s_waitcnt vmcnt(16)" ::: "memory");                       \
    } else {                                                                  \
      asm volatile("s_waitcnt vmcnt(0)" ::: "memory");                        \
    }                                                                         \
    PHASE_SYNC_IN;                                                            \
    __builtin_amdgcn_s_setprio(1); MFMA_Q(4); __builtin_amdgcn_s_setprio(0);  \
    PHASE_SYNC_OUT;                                                           \
  }

  // ---- prologue: A(t0)->buf0; B(t0)->sA->LDS buf0; B(t1)->sB in flight ----
  STAGE_A2(0, 0, 0);
  STAGE_A2(0, 0, 2);            // A t0: 4 gload_lds
  LOAD_B4(sA, 0, 0); LOAD_B4(sA, 0, 1); LOAD_B4(sA, 0, 2); LOAD_B4(sA, 0, 3);
  LOAD_B4(sB, BKT, 0); LOAD_B4(sB, BKT, 1); LOAD_B4(sB, BKT, 2); LOAD_B4(sB, BKT, 3);
  WRITE_B(sA, 0);               // compiler auto-waits sA (drains A t0 too)
  SCHED_FENCE;
  asm volatile("s_waitcnt vmcnt(16)" ::: "memory");   // keep sB in flight
  asm volatile("s_waitcnt lgkmcnt(0)" ::: "memory");
  __builtin_amdgcn_s_barrier();

  for (int kt = 0; kt < NKT; kt += 2) {
    K_TILE(kt,     sA, sB);     // loads B(kt+2)->sA, writes B(kt+1)=sB
    K_TILE(kt + 1, sB, sA);     // loads B(kt+3)->sB, writes B(kt+2)=sA
  }

  // --- epilogue: + bias, tanh-GELU (jax.nn.gelu approximate=True), fp32 out ---
  // gelu(v) = 0.5 v (1 + tanh(u)) = v / (1 + exp(-2u))
  const float* be = bias + (size_t)e * DOUT;
#pragma unroll
  for (int ni = 0; ni < 4; ++ni) {
    const int col = n0 + warp_n * 64 + ni * 16 + (lane & 15);
    const float bc = be[col];
#pragma unroll
    for (int mi = 0; mi < 8; ++mi) {
#pragma unroll
      for (int rr = 0; rr < 4; ++rr) {
        const int row = t0 + warp_m * 128 + mi * 16 + (lane >> 4) * 4 + rr;
        float v = acc[mi][ni][rr] + bc;
        const float u = 0.7978845608028654f * (v + 0.044715f * v * v * v);
        v = v / (1.0f + __expf(-2.0f * u));
        out[(size_t)row * DOUT + col] = v;
      }
    }
  }
}

extern "C" void kernel_launch(void* const* d_in, const int* in_sizes, int n_in,
                              void* d_out, int out_size, void* d_ws, size_t ws_size,
                              hipStream_t stream) {
  const float* x     = (const float*)d_in[0];
  // d_in[1] = expert_frequency: balanced by construction (512 each) -> unused
  const float* gamma = (const float*)d_in[2];
  const float* beta  = (const float*)d_in[3];
  const float* W     = (const float*)d_in[4];
  const float* bias  = (const float*)d_in[5];
  float* out = (float*)d_out;
  bf16* xn   = (bf16*)d_ws;    // 8192*1024 bf16 = 16 MiB scratch

  hipLaunchKernelGGL(ln_bf16_kernel, dim3(T_TOK), dim3(256), 0, stream,
                     x, gamma, beta, xn);
  hipLaunchKernelGGL(grouped_gemm_kernel, dim3((T_TOK / BM) * (DOUT / BN)),
                     dim3(512), 0, stream, xn, W, bias, out);
}

// Round 7
// 163.429 us; speedup vs baseline: 2.0627x; 2.0627x over previous
//
#include <hip/hip_runtime.h>
#include <hip/hip_bf16.h>

// ParallelExperts: per-expert LayerNorm -> Linear(1024->4096) -> tanh-GELU
// E=16 experts, 512 tokens each (balanced), fp32 in/out, bf16 MFMA inside.

#define E_EXP 16
#define T_TOK 8192
#define DIN   1024
#define DOUT  4096

typedef __bf16 bf16;
typedef __bf16 bf16x4v __attribute__((ext_vector_type(4)));
typedef __bf16 bf16x8v __attribute__((ext_vector_type(8)));
typedef float  f32x4   __attribute__((ext_vector_type(4)));

typedef __attribute__((address_space(1))) void gvoid;
typedef __attribute__((address_space(3))) void lvoid;

// ---------------- LayerNorm -> bf16 (one block per token) ----------------
__global__ __launch_bounds__(256) void ln_bf16_kernel(
    const float* __restrict__ x, const float* __restrict__ gamma,
    const float* __restrict__ beta, bf16* __restrict__ xn) {
  const int t    = blockIdx.x;
  const int e    = t >> 9;            // 512 tokens per expert
  const int tid  = threadIdx.x;
  const float4 xv = reinterpret_cast<const float4*>(x + (size_t)t * DIN)[tid];
  float s  = xv.x + xv.y + xv.z + xv.w;
  float s2 = xv.x * xv.x + xv.y * xv.y + xv.z * xv.z + xv.w * xv.w;
#pragma unroll
  for (int o = 32; o > 0; o >>= 1) {
    s  += __shfl_xor(s,  o, 64);
    s2 += __shfl_xor(s2, o, 64);
  }
  __shared__ float red[8];
  const int lane = tid & 63, wid = tid >> 6;
  if (lane == 0) { red[wid] = s; red[4 + wid] = s2; }
  __syncthreads();
  s  = red[0] + red[1] + red[2] + red[3];
  s2 = red[4] + red[5] + red[6] + red[7];
  const float mu  = s * (1.0f / DIN);
  const float var = s2 * (1.0f / DIN) - mu * mu;
  const float inv = rsqrtf(var + 1e-5f);
  const float4 g = reinterpret_cast<const float4*>(gamma + (size_t)e * DIN)[tid];
  const float4 b = reinterpret_cast<const float4*>(beta  + (size_t)e * DIN)[tid];
  bf16x4v o;
  o[0] = (bf16)((xv.x - mu) * inv * g.x + b.x);
  o[1] = (bf16)((xv.y - mu) * inv * g.y + b.y);
  o[2] = (bf16)((xv.z - mu) * inv * g.z + b.z);
  o[3] = (bf16)((xv.w - mu) * inv * g.w + b.w);
  *reinterpret_cast<bf16x4v*>(xn + (size_t)t * DIN + tid * 4) = o;
}

// ---------------- grouped GEMM: C = GELU(xn @ W[e] + b[e]) ----------------
// 256x256 tile, K-tile 64, 8 waves (2m x 4n), per-wave 128x64 output.
// 4 phases per K-tile, 16 MFMA each:
//   phase: [ds_reads | prefetch issue] -> barrier+lgkm0 -> setprio(1)
//          16xMFMA setprio(0) -> barrier
// Single B register set (16 x float2 = 32 VGPR): B(kt+1) loads issued in
// phases 0-1, cvt + swizzled ds_write early in phase 3 (~2.5 phases of
// latency cover). A(kt+1) via global_load_lds issued phases 0-1, drained by
// the end-of-tile vmcnt(0) (no young loads exist there -> free drain).
// Arch-VGPR budget: acc 128 AGPR + ~115 VGPR < 256 unified (2 waves/SIMD).
// A: gload_lds linear dest + pre-swizzled SOURCE (grp ^= row&7); B: ds_write
// grp ^= (n>>1)&7. Both verified 0-conflict in R6.
#define BM 256
#define BN 256
#define BKT 64
#define NKT (DIN / BKT)   // 16 K-tiles

#define SCHED_FENCE __builtin_amdgcn_sched_barrier(0)

__global__ __launch_bounds__(512, 2) void grouped_gemm_kernel(
    const bf16* __restrict__ xn, const float* __restrict__ W,
    const float* __restrict__ bias, float* __restrict__ out) {
  __shared__ bf16 Alds[2][BM * BKT];   // 2 x 32 KB, [m][64] grp^(m&7)
  __shared__ bf16 Blds[2][BN * BKT];   // 2 x 32 KB, [n][64] grp^((n>>1)&7)

  const int tid    = threadIdx.x;
  const int lane   = tid & 63;
  const int wid    = tid >> 6;       // 0..7
  const int warp_m = wid >> 2;       // 0..1
  const int warp_n = wid & 3;        // 0..3

  // bijective XCD swizzle: 512 blocks, 8 XCDs, 64 contiguous per XCD.
  const int swz    = (blockIdx.x & 7) * 64 + (blockIdx.x >> 3);
  const int ntile  = swz & 15;       // 0..15
  const int mtile  = swz >> 4;       // 0..31
  const int e      = mtile >> 1;     // 2 m-tiles per expert
  const int t0     = mtile * BM;
  const int n0     = ntile * BN;

  f32x4 acc[8][4];
#pragma unroll
  for (int i = 0; i < 8; ++i)
#pragma unroll
    for (int j = 0; j < 4; ++j)
      acc[i][j] = (f32x4){0.f, 0.f, 0.f, 0.f};

  const bf16*  Abase = xn + (size_t)t0 * DIN;
  const float* Wbase = W + (size_t)e * DIN * DOUT + n0;

  // fragment-read swizzle constants (lane-only)
  const int g0a  = (lane >> 4) ^ (lane & 7);          // A phys grp, ks=0
  const int h0b  = (lane >> 4) ^ ((lane >> 1) & 7);   // B phys grp, ks=0
  const int arow = warp_m * 128 + (lane & 15);
  const int brow = warp_n * 64 + (lane & 15);
  // A staging: logical source group so linear LDS dest ends up swizzled
  const int alg  = (lane & 7) ^ ((lane >> 3) & 7);

  // B staging ownership: col pair 2*np..2*np+1, k-quarter kq (16 k's)
  const int np = tid & 127;
  const int kq = tid >> 7;

  float2 sB[16];   // single B register set (32 VGPR)

#define STAGE_A2(buf, k0, J0)                                                 \
  {                                                                           \
    _Pragma("unroll")                                                         \
    for (int j = (J0); j < (J0) + 2; ++j) {                                   \
      const int c2 = wid * 4 + j;                  /* 0..31: rows c2*8..+7 */ \
      const bf16* g = Abase + (size_t)(c2 * 8 + (lane >> 3)) * DIN + (k0) +   \
                      alg * 8;                                                \
      __builtin_amdgcn_global_load_lds((gvoid*)g,                             \
                                       (lvoid*)&Alds[buf][c2 * 512], 16, 0, 0); \
    }                                                                         \
  }

#define LOAD_B4(k0, Q)                                                        \
  {                                                                           \
    _Pragma("unroll")                                                         \
    for (int r = 0; r < 4; ++r) {                                             \
      const int rr = (Q) * 4 + r;                                             \
      sB[rr] = *reinterpret_cast<const float2*>(                              \
          Wbase + (size_t)((k0) + kq * 16 + rr) * DOUT + 2 * np);             \
    }                                                                         \
  }

#define WRITE_B(buf)                                                          \
  {                                                                           \
    bf16x8v v0, v1, v2, v3;                                                   \
    _Pragma("unroll")                                                         \
    for (int r = 0; r < 8; ++r) {                                             \
      v0[r] = (bf16)sB[r].x;  v1[r] = (bf16)sB[r + 8].x;                      \
      v2[r] = (bf16)sB[r].y;  v3[r] = (bf16)sB[r + 8].y;                      \
    }                                                                         \
    const int c0 = 2 * np, slot = np & 7;                                     \
    *(bf16x8v*)&Blds[buf][c0 * BKT + (((2 * kq) ^ slot) * 8)]           = v0; \
    *(bf16x8v*)&Blds[buf][c0 * BKT + (((2 * kq + 1) ^ slot) * 8)]       = v1; \
    *(bf16x8v*)&Blds[buf][(c0 + 1) * BKT + (((2 * kq) ^ slot) * 8)]     = v2; \
    *(bf16x8v*)&Blds[buf][(c0 + 1) * BKT + (((2 * kq + 1) ^ slot) * 8)] = v3; \
  }

#define RD_A4(MIB, KS)                                                        \
  {                                                                           \
    _Pragma("unroll")                                                         \
    for (int mi = 0; mi < 4; ++mi)                                            \
      af[mi] = *reinterpret_cast<const bf16x8v*>(                             \
          &Alds[cur][(arow + ((MIB) + mi) * 16) * BKT +                       \
                     ((g0a ^ ((KS) * 4)) * 8)]);                              \
  }

#define RD_B4(KS)                                                             \
  {                                                                           \
    _Pragma("unroll")                                                         \
    for (int ni = 0; ni < 4; ++ni)                                            \
      bfr[ni] = *reinterpret_cast<const bf16x8v*>(                            \
          &Blds[cur][(brow + ni * 16) * BKT + ((h0b ^ ((KS) * 4)) * 8)]);     \
  }

#define MFMA_Q(MIB)                                                           \
  {                                                                           \
    _Pragma("unroll")                                                         \
    for (int mi = 0; mi < 4; ++mi)                                            \
      _Pragma("unroll")                                                       \
      for (int ni = 0; ni < 4; ++ni)                                          \
        acc[(MIB) + mi][ni] = __builtin_amdgcn_mfma_f32_16x16x32_bf16(        \
            af[mi], bfr[ni], acc[(MIB) + mi][ni], 0, 0, 0);                   \
  }

#define PHASE_SYNC_IN                                                         \
  SCHED_FENCE;                                                                \
  __builtin_amdgcn_s_barrier();                                               \
  asm volatile("s_waitcnt lgkmcnt(0)" ::: "memory");                          \
  SCHED_FENCE;

#define PHASE_SYNC_OUT                                                        \
  SCHED_FENCE;                                                                \
  __builtin_amdgcn_s_barrier();

// One K-tile = 4 phases x 16 MFMA. Prefetch of tile KT+1 (A chunks + B regs)
// is spread over phases 0-1; B cvt+ds_write lands early in phase 3.
#define K_TILE(KT)                                                            \
  {                                                                           \
    const int cur = (KT) & 1;                                                 \
    const bool pf = (KT) + 1 < NKT;                                           \
    bf16x8v af[4], bfr[4];                                                    \
    /* phase 0: ks=0, mi 0-3; issue A chunk0 + B Q0,Q1 of KT+1 */             \
    RD_A4(0, 0); RD_B4(0);                                                    \
    if (pf) {                                                                 \
      STAGE_A2(cur ^ 1, ((KT) + 1) * BKT, 0);                                 \
      LOAD_B4(((KT) + 1) * BKT, 0); LOAD_B4(((KT) + 1) * BKT, 1);             \
    }                                                                         \
    PHASE_SYNC_IN;                                                            \
    __builtin_amdgcn_s_setprio(1); MFMA_Q(0); __builtin_amdgcn_s_setprio(0);  \
    PHASE_SYNC_OUT;                                                           \
    /* phase 1: ks=0, mi 4-7; issue A chunk1 + B Q2,Q3 of KT+1 */             \
    RD_A4(4, 0);                                                              \
    if (pf) {                                                                 \
      STAGE_A2(cur ^ 1, ((KT) + 1) * BKT, 2);                                 \
      LOAD_B4(((KT) + 1) * BKT, 2); LOAD_B4(((KT) + 1) * BKT, 3);             \
    }                                                                         \
    PHASE_SYNC_IN;                                                            \
    __builtin_amdgcn_s_setprio(1); MFMA_Q(4); __builtin_amdgcn_s_setprio(0);  \
    PHASE_SYNC_OUT;                                                           \
    /* phase 2: ks=1, mi 0-3 */                                               \
    RD_A4(0, 1); RD_B4(1);                                                    \
    PHASE_SYNC_IN;                                                            \
    __builtin_amdgcn_s_setprio(1); MFMA_Q(0); __builtin_amdgcn_s_setprio(0);  \
    PHASE_SYNC_OUT;                                                           \
    /* phase 3: ks=1, mi 4-7; cvt+write B(KT+1) before MFMA */                \
    RD_A4(4, 1);                                                              \
    if (pf) { WRITE_B(cur ^ 1); }   /* cvt waits its own B loads only */      \
    PHASE_SYNC_IN;                                                            \
    __builtin_amdgcn_s_setprio(1); MFMA_Q(4); __builtin_amdgcn_s_setprio(0);  \
    if (pf) {                                                                 \
      SCHED_FENCE;                                                            \
      asm volatile("s_waitcnt vmcnt(0)" ::: "memory");  /* A(KT+1) staged */  \
      __builtin_amdgcn_s_barrier();                                           \
      asm volatile("" ::: "memory");                                          \
    }                                                                         \
  }

  // ---- prologue: A(t0)->buf0; B(t0)->sB->LDS buf0 ----
  STAGE_A2(0, 0, 0);
  STAGE_A2(0, 0, 2);            // A t0: 4 gload_lds
  LOAD_B4(0, 0); LOAD_B4(0, 1); LOAD_B4(0, 2); LOAD_B4(0, 3);
  WRITE_B(0);                   // cvt auto-waits B t0 loads
  SCHED_FENCE;
  asm volatile("s_waitcnt vmcnt(0)" ::: "memory");
  asm volatile("s_waitcnt lgkmcnt(0)" ::: "memory");
  __builtin_amdgcn_s_barrier();
  asm volatile("" ::: "memory");

  for (int kt = 0; kt < NKT; ++kt) {
    K_TILE(kt);
  }

  // --- epilogue: + bias, tanh-GELU (jax.nn.gelu approximate=True), fp32 out ---
  // gelu(v) = 0.5 v (1 + tanh(u)) = v / (1 + exp(-2u))
  const float* be = bias + (size_t)e * DOUT;
#pragma unroll
  for (int ni = 0; ni < 4; ++ni) {
    const int col = n0 + warp_n * 64 + ni * 16 + (lane & 15);
    const float bc = be[col];
#pragma unroll
    for (int mi = 0; mi < 8; ++mi) {
#pragma unroll
      for (int rr = 0; rr < 4; ++rr) {
        const int row = t0 + warp_m * 128 + mi * 16 + (lane >> 4) * 4 + rr;
        float v = acc[mi][ni][rr] + bc;
        const float u = 0.7978845608028654f * (v + 0.044715f * v * v * v);
        v = v / (1.0f + __expf(-2.0f * u));
        out[(size_t)row * DOUT + col] = v;
      }
    }
  }
}

extern "C" void kernel_launch(void* const* d_in, const int* in_sizes, int n_in,
                              void* d_out, int out_size, void* d_ws, size_t ws_size,
                              hipStream_t stream) {
  const float* x     = (const float*)d_in[0];
  // d_in[1] = expert_frequency: balanced by construction (512 each) -> unused
  const float* gamma = (const float*)d_in[2];
  const float* beta  = (const float*)d_in[3];
  const float* W     = (const float*)d_in[4];
  const float* bias  = (const float*)d_in[5];
  float* out = (float*)d_out;
  bf16* xn   = (bf16*)d_ws;    // 8192*1024 bf16 = 16 MiB scratch

  hipLaunchKernelGGL(ln_bf16_kernel, dim3(T_TOK), dim3(256), 0, stream,
                     x, gamma, beta, xn);
  hipLaunchKernelGGL(grouped_gemm_kernel, dim3((T_TOK / BM) * (DOUT / BN)),
                     dim3(512), 0, stream, xn, W, bias, out);
}

// Round 8
// 146.697 us; speedup vs baseline: 2.2980x; 1.1141x over previous
//
#include <hip/hip_runtime.h>
#include <hip/hip_bf16.h>

// ParallelExperts: per-expert LayerNorm -> Linear(1024->4096) -> tanh-GELU
// E=16 experts, 512 tokens each (balanced), fp32 in/out, bf16 MFMA inside.

#define E_EXP 16
#define T_TOK 8192
#define DIN   1024
#define DOUT  4096

typedef __bf16 bf16;
typedef __bf16 bf16x4v __attribute__((ext_vector_type(4)));
typedef __bf16 bf16x8v __attribute__((ext_vector_type(8)));
typedef float  f32x4   __attribute__((ext_vector_type(4)));

typedef __attribute__((address_space(1))) void gvoid;
typedef __attribute__((address_space(3))) void lvoid;

// ---------------- LayerNorm -> bf16 (one block per token) ----------------
__global__ __launch_bounds__(256) void ln_bf16_kernel(
    const float* __restrict__ x, const float* __restrict__ gamma,
    const float* __restrict__ beta, bf16* __restrict__ xn) {
  const int t    = blockIdx.x;
  const int e    = t >> 9;            // 512 tokens per expert
  const int tid  = threadIdx.x;
  const float4 xv = reinterpret_cast<const float4*>(x + (size_t)t * DIN)[tid];
  float s  = xv.x + xv.y + xv.z + xv.w;
  float s2 = xv.x * xv.x + xv.y * xv.y + xv.z * xv.z + xv.w * xv.w;
#pragma unroll
  for (int o = 32; o > 0; o >>= 1) {
    s  += __shfl_xor(s,  o, 64);
    s2 += __shfl_xor(s2, o, 64);
  }
  __shared__ float red[8];
  const int lane = tid & 63, wid = tid >> 6;
  if (lane == 0) { red[wid] = s; red[4 + wid] = s2; }
  __syncthreads();
  s  = red[0] + red[1] + red[2] + red[3];
  s2 = red[4] + red[5] + red[6] + red[7];
  const float mu  = s * (1.0f / DIN);
  const float var = s2 * (1.0f / DIN) - mu * mu;
  const float inv = rsqrtf(var + 1e-5f);
  const float4 g = reinterpret_cast<const float4*>(gamma + (size_t)e * DIN)[tid];
  const float4 b = reinterpret_cast<const float4*>(beta  + (size_t)e * DIN)[tid];
  bf16x4v o;
  o[0] = (bf16)((xv.x - mu) * inv * g.x + b.x);
  o[1] = (bf16)((xv.y - mu) * inv * g.y + b.y);
  o[2] = (bf16)((xv.z - mu) * inv * g.z + b.z);
  o[3] = (bf16)((xv.w - mu) * inv * g.w + b.w);
  *reinterpret_cast<bf16x4v*>(xn + (size_t)t * DIN + tid * 4) = o;
}

// ---------------- grouped GEMM: C = GELU(xn @ W[e] + b[e]) ----------------
// 256x256 tile, BK=32, 8 waves (2m x 4n), per-wave 128x64 output.
// MLP fix: B (W fp32 [k][n]) staged DIRECTLY to LDS via global_load_lds
// (no register staging -> in-flight state lives in the VMEM FIFO, not VGPRs).
// Triple-buffered A (3x16KB bf16) and B (3x32KB fp32) = 144 KB LDS; stage
// distance = 2 K-steps; one barrier per K-step with counted vmcnt(6): the
// 6 loads of tile kt+2 stay in flight across every barrier.
// B conversion fp32->bf16 happens at fragment read (8x ds_read_b32 + cvt).
// B LDS rotation swizzle: within each 256B window of a k-row, 16B-group
// gsub is rotated by 4*((r>>3)&3) -- applied on the global SOURCE address
// (linear LDS dest, rule-#21) and on the read address; column reads become
// 2-way (free). A at BK=32 (64B rows) is naturally ~2-way: no swizzle.
#define BM 256
#define BN 256
#define BK 32
#define NK (DIN / BK)   // 32 K-steps

#define SCHED_FENCE __builtin_amdgcn_sched_barrier(0)

__global__ __launch_bounds__(512, 2) void grouped_gemm_kernel(
    const bf16* __restrict__ xn, const float* __restrict__ W,
    const float* __restrict__ bias, float* __restrict__ out) {
  __shared__ bf16  Alds[3][BM * BK];   // 3 x 16 KB, [m][32k] linear
  __shared__ float Blds[3][BK * BN];   // 3 x 32 KB, [k][256n] rotated windows

  const int tid    = threadIdx.x;
  const int lane   = tid & 63;
  const int wid    = tid >> 6;       // 0..7
  const int warp_m = wid >> 2;       // 0..1
  const int warp_n = wid & 3;        // 0..3
  const int q      = lane >> 4;      // 0..3 (k-group of this lane)
  const int lp     = lane & 15;

  // bijective XCD swizzle: 512 blocks, 8 XCDs, 64 contiguous per XCD.
  const int swz    = (blockIdx.x & 7) * 64 + (blockIdx.x >> 3);
  const int ntile  = swz & 15;       // 0..15
  const int mtile  = swz >> 4;       // 0..31
  const int e      = mtile >> 1;     // 2 m-tiles per expert
  const int t0     = mtile * BM;
  const int n0     = ntile * BN;

  f32x4 acc[8][4];
#pragma unroll
  for (int i = 0; i < 8; ++i)
#pragma unroll
    for (int j = 0; j < 4; ++j)
      acc[i][j] = (f32x4){0.f, 0.f, 0.f, 0.f};

  const bf16*  Abase = xn + (size_t)t0 * DIN;
  const float* Wexp  = W + (size_t)e * DIN * DOUT + n0;

  // B fragment read offsets (float elements, within a buffer):
  // row r = q*8+j -> r*256 ; window warp_n (64 cols) ; rotated gsub
  // phys = ((ni+q)&3)*16 + lp ; j adds j*256.
  int Voff[4];
#pragma unroll
  for (int ni = 0; ni < 4; ++ni)
    Voff[ni] = q * 2048 + warp_n * 64 + (((ni + q) & 3) * 16) + lp;

  // A staging: 2 insts/thread; inst ci covers rows ci*16..+15 (16 rows x 64B
  // = 1KB); lane l -> row (l>>2), 16B-group l&3. Linear dest & source.
#define STAGE_A(buf, k0)                                                      \
  {                                                                           \
    _Pragma("unroll")                                                         \
    for (int c = 0; c < 2; ++c) {                                             \
      const int ci = wid * 2 + c;                   /* 0..15 */               \
      const bf16* g = Abase + (size_t)(ci * 16 + (lane >> 2)) * DIN + (k0) +  \
                      (lane & 3) * 8;                                         \
      __builtin_amdgcn_global_load_lds((gvoid*)g,                             \
                                       (lvoid*)&Alds[buf][ci * 512], 16, 0, 0); \
    }                                                                         \
  }

  // B staging: 4 insts/thread; inst p covers k-row r = p*8 + wid (1KB row).
  // dest lane l -> window q=l>>4, gsub l&15 (linear). Source gsub rotated by
  // -4p within the window ((r>>3)&3 == p for this row assignment).
#define STAGE_B(buf, k0)                                                      \
  {                                                                           \
    _Pragma("unroll")                                                         \
    for (int p = 0; p < 4; ++p) {                                             \
      const char* src =                                                       \
          (const char*)(Wexp + (size_t)((k0) + p * 8 + wid) * DOUT) +         \
          q * 256 + (((lp - 4 * p) & 15) * 16);                               \
      __builtin_amdgcn_global_load_lds((gvoid*)src,                           \
          (lvoid*)&Blds[buf][(p * 8 + wid) * 256], 16, 0, 0);                 \
    }                                                                         \
  }

#define BAR_VM(N)                                                             \
  {                                                                           \
    SCHED_FENCE;                                                              \
    asm volatile("s_waitcnt vmcnt(" #N ")" ::: "memory");                     \
    __builtin_amdgcn_s_barrier();                                             \
    asm volatile("" ::: "memory");                                            \
  }

// One K-step. AB/ST = compile-time buffer indices (current / staging target).
// Issue stage(KT+2) first (enters FIFO early), then ds_reads + cvt + MFMA.
#define K_STEP(KT, AB, ST, STG)                                               \
  {                                                                           \
    if (STG) { STAGE_A(ST, ((KT) + 2) * BK); STAGE_B(ST, ((KT) + 2) * BK); }  \
    SCHED_FENCE;                                                              \
    bf16x8v af[8], bfr[4];                                                    \
    _Pragma("unroll")                                                         \
    for (int mi = 0; mi < 8; ++mi)                                            \
      af[mi] = *reinterpret_cast<const bf16x8v*>(                             \
          &Alds[AB][(warp_m * 128 + mi * 16 + lp) * BK + q * 8]);             \
    _Pragma("unroll")                                                         \
    for (int ni = 0; ni < 4; ++ni) {                                          \
      const float* pB = &Blds[AB][Voff[ni]];                                  \
      _Pragma("unroll")                                                       \
      for (int j = 0; j < 8; ++j) bfr[ni][j] = (bf16)pB[j * 256];             \
    }                                                                         \
    _Pragma("unroll")                                                         \
    for (int mi = 0; mi < 8; ++mi)                                            \
      _Pragma("unroll")                                                       \
      for (int ni = 0; ni < 4; ++ni)                                          \
        acc[mi][ni] = __builtin_amdgcn_mfma_f32_16x16x32_bf16(                \
            af[mi], bfr[ni], acc[mi][ni], 0, 0, 0);                           \
  }

  // ---- prologue: stage tiles 0,1 into buffers 0,1 (12 VMEM/thread) ----
  STAGE_A(0, 0);  STAGE_B(0, 0);
  STAGE_A(1, BK); STAGE_B(1, BK);
  BAR_VM(6);   // tile 0 complete; tile 1's 6 loads stay in flight

  // Steady state: step kt reads buf kt%3, stages tile kt+2 into (kt+2)%3.
  // Barrier vmcnt(6): drains stage(kt+1) (read next step), leaves stage(kt+2).
  for (int kt = 0; kt < 30; kt += 3) {
    K_STEP(kt,     0, 2, 1); BAR_VM(6);
    K_STEP(kt + 1, 1, 0, 1); BAR_VM(6);
    K_STEP(kt + 2, 2, 1, 1); BAR_VM(6);
  }
  K_STEP(30, 0, 0, 0); BAR_VM(0);   // drain tile 31's loads
  K_STEP(31, 1, 0, 0);              // final K-step, no barrier

  // --- epilogue: + bias, tanh-GELU (jax.nn.gelu approximate=True), fp32 out ---
  // gelu(v) = 0.5 v (1 + tanh(u)) = v / (1 + exp(-2u))
  const float* be = bias + (size_t)e * DOUT;
#pragma unroll
  for (int ni = 0; ni < 4; ++ni) {
    const int col = n0 + warp_n * 64 + ni * 16 + lp;
    const float bc = be[col];
#pragma unroll
    for (int mi = 0; mi < 8; ++mi) {
#pragma unroll
      for (int rr = 0; rr < 4; ++rr) {
        const int row = t0 + warp_m * 128 + mi * 16 + q * 4 + rr;
        float v = acc[mi][ni][rr] + bc;
        const float u = 0.7978845608028654f * (v + 0.044715f * v * v * v);
        v = v / (1.0f + __expf(-2.0f * u));
        out[(size_t)row * DOUT + col] = v;
      }
    }
  }
}

extern "C" void kernel_launch(void* const* d_in, const int* in_sizes, int n_in,
                              void* d_out, int out_size, void* d_ws, size_t ws_size,
                              hipStream_t stream) {
  const float* x     = (const float*)d_in[0];
  // d_in[1] = expert_frequency: balanced by construction (512 each) -> unused
  const float* gamma = (const float*)d_in[2];
  const float* beta  = (const float*)d_in[3];
  const float* W     = (const float*)d_in[4];
  const float* bias  = (const float*)d_in[5];
  float* out = (float*)d_out;
  bf16* xn   = (bf16*)d_ws;    // 8192*1024 bf16 = 16 MiB scratch

  hipLaunchKernelGGL(ln_bf16_kernel, dim3(T_TOK), dim3(256), 0, stream,
                     x, gamma, beta, xn);
  hipLaunchKernelGGL(grouped_gemm_kernel, dim3((T_TOK / BM) * (DOUT / BN)),
                     dim3(512), 0, stream, xn, W, bias, out);
}